// Round 1
// 2700.517 us; speedup vs baseline: 1.6968x; 1.6968x over previous
//
#include <hip/hip_runtime.h>
#include <math.h>

#define Bsz  8192
#define Mdim 512
#define Ndim 2048
#define Kit  16
#define Pk   50
#define EPSv 0.01f

typedef __attribute__((ext_vector_type(8))) short bf16x8;
typedef __attribute__((ext_vector_type(4))) float f32x4;

// ---- bf16 split helpers: x = h + l ----------------------------------------
static __device__ __forceinline__ unsigned short f2bf(float f) {
    unsigned u = __float_as_uint(f);
    return (unsigned short)((u + 0x7fffu + ((u >> 16) & 1u)) >> 16);  // RNE
}
static __device__ __forceinline__ float bf2f(unsigned short h) {
    return __uint_as_float(((unsigned)h) << 16);
}

// ---- async global->LDS, 16B per lane --------------------------------------
static __device__ __forceinline__ void gl16(const void* g, void* l) {
    __builtin_amdgcn_global_load_lds(
        (const __attribute__((address_space(1))) unsigned int*)g,
        (__attribute__((address_space(3))) unsigned int*)l, 16, 0, 0);
}

// ---------------------------------------------------------------------------
// One-time: split A into bf16 planes Ah/Al [m][n] and AhT/AlT [n][m].
// ---------------------------------------------------------------------------
__global__ __launch_bounds__(256) void presplit_A(
    const float* __restrict__ A, unsigned short* __restrict__ Ah,
    unsigned short* __restrict__ Al, unsigned short* __restrict__ AhT,
    unsigned short* __restrict__ AlT)
{
    int idx = blockIdx.x * 256 + threadIdx.x;      // 0 .. M*N-1
    int m = idx >> 11, n = idx & (Ndim - 1);
    float a = A[idx];
    unsigned short h = f2bf(a);
    unsigned short l = f2bf(a - bf2f(h));
    Ah[idx] = h; Al[idx] = l;
    AhT[(size_t)n * Mdim + m] = h;
    AlT[(size_t)n * Mdim + m] = l;
}

// ---------------------------------------------------------------------------
// it=0: b = -y, stored as h/l planes. b row layout: [h 512][l 512] shorts.
// ---------------------------------------------------------------------------
__global__ __launch_bounds__(256) void split_negy_kernel(const float* __restrict__ y,
                                                         unsigned short* __restrict__ bS) {
    int i = blockIdx.x * 256 + threadIdx.x;        // float4 index
    float4 v = ((const float4*)y)[i];
    int idx = i * 4;
    int r = idx >> 9, c = idx & 511;
    float f0 = -v.x, f1 = -v.y, f2 = -v.z, f3 = -v.w;
    unsigned short h0 = f2bf(f0), h1 = f2bf(f1), h2 = f2bf(f2), h3 = f2bf(f3);
    ushort4 hv = make_ushort4(h0, h1, h2, h3);
    ushort4 lv = make_ushort4(f2bf(f0 - bf2f(h0)), f2bf(f1 - bf2f(h1)),
                              f2bf(f2 - bf2f(h2)), f2bf(f3 - bf2f(h3)));
    *(ushort4*)(bS + (size_t)r * 1024 + c)       = hv;
    *(ushort4*)(bS + (size_t)r * 1024 + 512 + c) = lv;
}

// ---------------------------------------------------------------------------
// GEMM1 (NT): b[r][m] = sum_n z[r][n]*A[m][n] - y[r][m].
// z planes: zS row r = shorts [r*4096 .. ): [zh 2048][zl 2048].
// Tile 128(r)x64(m), BK=64. Staging: global_load_lds w=16, XOR-swizzled
// source (X=(row&7)<<4 within 128B rows) + same XOR on ds_read_b128.
// LDS 48KB -> 3 blocks/CU.
// ---------------------------------------------------------------------------
__global__ __launch_bounds__(256) void gemm1_mfma(
    const unsigned short* __restrict__ zS,
    const unsigned short* __restrict__ Ah, const unsigned short* __restrict__ Al,
    const float* __restrict__ y, unsigned short* __restrict__ bS)
{
    const int tid  = threadIdx.x;
    const int lane = tid & 63, w = tid >> 6;
    const int lm   = lane & 15, quad = lane >> 4;
    const int wr   = (w & 1) * 64, wm = (w >> 1) * 32;

    // bijective XCD swizzle (nwg=512, %8==0)
    int d   = blockIdx.y * gridDim.x + blockIdx.x;
    int sid = (d & 7) * 64 + (d >> 3);
    const int m0 = (sid & 7) * 64, r0 = (sid >> 3) * 128;

    __shared__ __attribute__((aligned(16))) unsigned short zh_s[128 * 64];
    __shared__ __attribute__((aligned(16))) unsigned short zl_s[128 * 64];
    __shared__ __attribute__((aligned(16))) unsigned short ah_s[64 * 64];
    __shared__ __attribute__((aligned(16))) unsigned short al_s[64 * 64];

    f32x4 acc[4][2];
#pragma unroll
    for (int i = 0; i < 4; i++)
#pragma unroll
        for (int j = 0; j < 2; j++) acc[i][j] = (f32x4)0.f;

    // staging descriptors: z plane = 16KB = 16 chunks of 1KB; 4/wave.
    const unsigned short* zsh[4]; const unsigned short* zsl[4]; int zoff[4];
#pragma unroll
    for (int s = 0; s < 4; s++) {
        int off = ((w * 4 + s) << 10) + lane * 16;
        int row = off >> 7;
        int kb  = (off & 127) ^ ((row & 7) << 4);
        zoff[s] = (w * 4 + s) << 10;
        zsh[s]  = zS + (size_t)(r0 + row) * 4096 + (kb >> 1);
        zsl[s]  = zS + (size_t)(r0 + row) * 4096 + 2048 + (kb >> 1);
    }
    // A plane = 8KB = 8 chunks; 2/wave.
    const unsigned short* ash[2]; const unsigned short* asl[2]; int aoff[2];
#pragma unroll
    for (int s = 0; s < 2; s++) {
        int off = ((w * 2 + s) << 10) + lane * 16;
        int row = off >> 7;
        int kb  = (off & 127) ^ ((row & 7) << 4);
        aoff[s] = (w * 2 + s) << 10;
        ash[s]  = Ah + (size_t)(m0 + row) * 2048 + (kb >> 1);
        asl[s]  = Al + (size_t)(m0 + row) * 2048 + (kb >> 1);
    }

    const int X = (lm & 7) << 4;   // all fragment rows have row&7 == lm&7

    for (int k0 = 0; k0 < Ndim; k0 += 64) {
        __syncthreads();
#pragma unroll
        for (int s = 0; s < 4; s++) {
            gl16(zsh[s], (char*)zh_s + zoff[s]);
            gl16(zsl[s], (char*)zl_s + zoff[s]);
            zsh[s] += 64; zsl[s] += 64;
        }
#pragma unroll
        for (int s = 0; s < 2; s++) {
            gl16(ash[s], (char*)ah_s + aoff[s]);
            gl16(asl[s], (char*)al_s + aoff[s]);
            ash[s] += 64; asl[s] += 64;
        }
        __syncthreads();   // compiler drains vmcnt(0) here -> tile ready
#pragma unroll
        for (int kk = 0; kk < 2; kk++) {
            const int cbx = (kk * 64 + quad * 16) ^ X;
            bf16x8 bhf[2], blf[2];
#pragma unroll
            for (int fj = 0; fj < 2; fj++) {
                int ar = wm + fj * 16 + lm;
                bhf[fj] = *(const bf16x8*)((const char*)ah_s + ar * 128 + cbx);
                blf[fj] = *(const bf16x8*)((const char*)al_s + ar * 128 + cbx);
            }
#pragma unroll
            for (int fi = 0; fi < 4; fi++) {
                int zr = wr + fi * 16 + lm;
                bf16x8 zh8 = *(const bf16x8*)((const char*)zh_s + zr * 128 + cbx);
                bf16x8 zl8 = *(const bf16x8*)((const char*)zl_s + zr * 128 + cbx);
#pragma unroll
                for (int fj = 0; fj < 2; fj++) {
                    acc[fi][fj] = __builtin_amdgcn_mfma_f32_16x16x32_bf16(zh8, bhf[fj], acc[fi][fj], 0, 0, 0);
                    acc[fi][fj] = __builtin_amdgcn_mfma_f32_16x16x32_bf16(zh8, blf[fj], acc[fi][fj], 0, 0, 0);
                    acc[fi][fj] = __builtin_amdgcn_mfma_f32_16x16x32_bf16(zl8, bhf[fj], acc[fi][fj], 0, 0, 0);
                }
            }
        }
    }
    // epilogue: subtract y, split to planes.  D: col=lane&15, row=quad*4+r
#pragma unroll
    for (int fi = 0; fi < 4; fi++)
#pragma unroll
        for (int fj = 0; fj < 2; fj++)
#pragma unroll
            for (int r = 0; r < 4; r++) {
                int row = r0 + wr + fi * 16 + quad * 4 + r;
                int col = m0 + wm + fj * 16 + lm;
                float bv = acc[fi][fj][r] - y[(size_t)row * Mdim + col];
                unsigned short h = f2bf(bv);
                bS[(size_t)row * 1024 + col]       = h;
                bS[(size_t)row * 1024 + 512 + col] = f2bf(bv - bf2f(h));
            }
}

// ---------------------------------------------------------------------------
// GEMM2 (NN): c[r][n] = sum_m b[r][m]*A[m][n], c fp32.
// Tile 128x128, BK=32, LDS 32KB. Same DMA+XOR scheme (64B rows, X=(row&3)<<4).
// ---------------------------------------------------------------------------
__global__ __launch_bounds__(256) void gemm2_mfma(
    const unsigned short* __restrict__ bS,
    const unsigned short* __restrict__ AhT, const unsigned short* __restrict__ AlT,
    float* __restrict__ c)
{
    const int tid  = threadIdx.x;
    const int lane = tid & 63, w = tid >> 6;
    const int lm   = lane & 15, quad = lane >> 4;
    const int wr   = (w & 1) * 64, wn = (w >> 1) * 64;

    // bijective XCD swizzle (nwg=1024, %8==0)
    int d   = blockIdx.y * gridDim.x + blockIdx.x;
    int sid = (d & 7) * 128 + (d >> 3);
    const int n0 = (sid & 15) * 128, r0 = (sid >> 4) * 128;

    __shared__ __attribute__((aligned(16))) unsigned short bh_s[128 * 32];
    __shared__ __attribute__((aligned(16))) unsigned short bl_s[128 * 32];
    __shared__ __attribute__((aligned(16))) unsigned short ath_s[128 * 32];
    __shared__ __attribute__((aligned(16))) unsigned short atl_s[128 * 32];

    f32x4 acc[4][4];
#pragma unroll
    for (int i = 0; i < 4; i++)
#pragma unroll
        for (int j = 0; j < 4; j++) acc[i][j] = (f32x4)0.f;

    // each plane = 8KB = 8 chunks of 1KB; 2/wave/plane.
    const unsigned short *bsh[2], *bsl[2], *ash[2], *asl[2]; int coff[2];
#pragma unroll
    for (int s = 0; s < 2; s++) {
        int off = ((w * 2 + s) << 10) + lane * 16;
        int row = off >> 6;
        int kb  = (off & 63) ^ ((row & 3) << 4);
        coff[s] = (w * 2 + s) << 10;
        bsh[s]  = bS  + (size_t)(r0 + row) * 1024 + (kb >> 1);
        bsl[s]  = bS  + (size_t)(r0 + row) * 1024 + 512 + (kb >> 1);
        ash[s]  = AhT + (size_t)(n0 + row) * 512 + (kb >> 1);
        asl[s]  = AlT + (size_t)(n0 + row) * 512 + (kb >> 1);
    }

    const int X = (lm & 3) << 4;

    for (int k0 = 0; k0 < Mdim; k0 += 32) {
        __syncthreads();
#pragma unroll
        for (int s = 0; s < 2; s++) {
            gl16(bsh[s], (char*)bh_s + coff[s]);
            gl16(bsl[s], (char*)bl_s + coff[s]);
            gl16(ash[s], (char*)ath_s + coff[s]);
            gl16(asl[s], (char*)atl_s + coff[s]);
            bsh[s] += 32; bsl[s] += 32; ash[s] += 32; asl[s] += 32;
        }
        __syncthreads();
        const int cbx = (quad * 16) ^ X;
        bf16x8 ahf[4], alf[4];
#pragma unroll
        for (int fj = 0; fj < 4; fj++) {
            int ar = wn + fj * 16 + lm;
            ahf[fj] = *(const bf16x8*)((const char*)ath_s + ar * 64 + cbx);
            alf[fj] = *(const bf16x8*)((const char*)atl_s + ar * 64 + cbx);
        }
#pragma unroll
        for (int fi = 0; fi < 4; fi++) {
            int br = wr + fi * 16 + lm;
            bf16x8 bh8 = *(const bf16x8*)((const char*)bh_s + br * 64 + cbx);
            bf16x8 bl8 = *(const bf16x8*)((const char*)bl_s + br * 64 + cbx);
#pragma unroll
            for (int fj = 0; fj < 4; fj++) {
                acc[fi][fj] = __builtin_amdgcn_mfma_f32_16x16x32_bf16(bh8, ahf[fj], acc[fi][fj], 0, 0, 0);
                acc[fi][fj] = __builtin_amdgcn_mfma_f32_16x16x32_bf16(bh8, alf[fj], acc[fi][fj], 0, 0, 0);
                acc[fi][fj] = __builtin_amdgcn_mfma_f32_16x16x32_bf16(bl8, ahf[fj], acc[fi][fj], 0, 0, 0);
            }
        }
    }
#pragma unroll
    for (int fi = 0; fi < 4; fi++)
#pragma unroll
        for (int fj = 0; fj < 4; fj++)
#pragma unroll
            for (int r = 0; r < 4; r++) {
                int row = r0 + wr + fi * 16 + quad * 4 + r;
                int col = n0 + wn + fj * 16 + lm;
                c[(size_t)row * Ndim + col] = acc[fi][fj][r];
            }
}

// ---------------------------------------------------------------------------
// Fused per-row: u = x - gamma*c; exact 50th-largest |u| (radix select);
// soft-threshold + overshoot; write x; write z as h/l planes in place of c.
// (reads complete before the radix barriers; plane writes after -> safe)
// ---------------------------------------------------------------------------
__global__ __launch_bounds__(256) void topk_update_kernel(
    float* __restrict__ uz, float* __restrict__ x,
    const float* __restrict__ gamma, const float* __restrict__ theta,
    const float* __restrict__ a_param, const float* __restrict__ vv,
    const float* __restrict__ vu, int it)
{
    const int row = blockIdx.x;
    const int t   = threadIdx.x;
    float* crow = uz + (size_t)row * Ndim;
    float* xrow = x  + (size_t)row * Ndim;
    const float g = gamma[it];

    float4 c0 = *(const float4*)(crow + 4 * t);
    float4 c1 = *(const float4*)(crow + 4 * t + 1024);
    float4 x0 = *(const float4*)(xrow + 4 * t);
    float4 x1 = *(const float4*)(xrow + 4 * t + 1024);
    float cv[8] = { c0.x, c0.y, c0.z, c0.w, c1.x, c1.y, c1.z, c1.w };
    float xv[8] = { x0.x, x0.y, x0.z, x0.w, x1.x, x1.y, x1.z, x1.w };

    float uvals[8];
    unsigned keys[8];
#pragma unroll
    for (int e = 0; e < 8; e++) {
        uvals[e] = xv[e] - g * cv[e];
        keys[e]  = __float_as_uint(fabsf(uvals[e]));
    }

    __shared__ unsigned bins[256];
    __shared__ unsigned sel[2];

    unsigned prefix = 0;
    unsigned k = Pk;
#pragma unroll
    for (int pass = 0; pass < 4; ++pass) {
        const int shift = 24 - pass * 8;
        bins[t] = 0;
        __syncthreads();
        const unsigned himask = (pass == 0) ? 0u : (0xFFFFFFFFu << (shift + 8));
#pragma unroll
        for (int e = 0; e < 8; e++) {
            if ((keys[e] & himask) == prefix)
                atomicAdd(&bins[(keys[e] >> shift) & 255], 1u);
        }
        __syncthreads();
        if (t < 64) {
            const int i0 = 255 - 4 * t;
            unsigned c0b = bins[i0], c1b = bins[i0 - 1];
            unsigned c2b = bins[i0 - 2], c3b = bins[i0 - 3];
            unsigned s = c0b + c1b + c2b + c3b;
            unsigned sc = s;
#pragma unroll
            for (int off = 1; off < 64; off <<= 1) {
                unsigned o = __shfl_up(sc, (unsigned)off);
                if (t >= off) sc += o;
            }
            unsigned pre = sc - s;
            unsigned cs[4] = { c0b, c1b, c2b, c3b };
#pragma unroll
            for (int j = 0; j < 4; j++) {
                unsigned cb = cs[j];
                if (pre < k && pre + cb >= k) { sel[0] = (unsigned)(i0 - j); sel[1] = k - pre; }
                pre += cb;
            }
        }
        __syncthreads();
        prefix |= sel[0] << shift;
        k = sel[1];
    }
    const float thresh = __uint_as_float(prefix);

    const float th = theta[it];
    const float ap = a_param[it];
    const bool haveNext = (it + 1) < Kit;
    float tn = 0.f, vn = 0.f, vun = 0.f;
    if (haveNext) { tn = theta[it + 1]; vn = vv[it + 1]; vun = vu[it + 1]; }

    float xo[8];
    unsigned short zh8[8], zl8[8];
#pragma unroll
    for (int e = 0; e < 8; e++) {
        float uval = uvals[e];
        float au   = fabsf(uval);
        bool keep  = au > thresh;
        float shr  = copysignf(fmaxf(au - th, 0.f), uval);
        float xn   = keep ? uval : shr;
        float dlt  = xn - xv[e];
        float ov   = 1.f + ap / (fabsf(dlt) + EPSv);
        float xr   = xv[e] + ov * dlt;
        xo[e] = xr;
        float z = (1.f + tn * vun * __expf(-vn * fabsf(xr))) * xr;
        unsigned short h = f2bf(z);
        zh8[e] = h;
        zl8[e] = f2bf(z - bf2f(h));
    }
    float4 a0 = { xo[0], xo[1], xo[2], xo[3] };
    float4 a1 = { xo[4], xo[5], xo[6], xo[7] };
    *(float4*)(xrow + 4 * t) = a0;
    *(float4*)(xrow + 4 * t + 1024) = a1;
    if (haveNext) {
        unsigned short* zp = (unsigned short*)crow;   // row block: [zh 2048][zl 2048]
        *(ushort4*)(zp + 4 * t)        = make_ushort4(zh8[0], zh8[1], zh8[2], zh8[3]);
        *(ushort4*)(zp + 1024 + 4 * t) = make_ushort4(zh8[4], zh8[5], zh8[6], zh8[7]);
        *(ushort4*)(zp + 2048 + 4 * t) = make_ushort4(zl8[0], zl8[1], zl8[2], zl8[3]);
        *(ushort4*)(zp + 3072 + 4 * t) = make_ushort4(zl8[4], zl8[5], zl8[6], zl8[7]);
    }
}

// ---------------------------------------------------------------------------
extern "C" void kernel_launch(void* const* d_in, const int* in_sizes, int n_in,
                              void* d_out, int out_size, void* d_ws, size_t ws_size,
                              hipStream_t stream) {
    const float* y       = (const float*)d_in[0];   // (B,M)
    const float* A       = (const float*)d_in[1];   // (M,N)
    const float* gamma   = (const float*)d_in[2];
    const float* theta   = (const float*)d_in[3];
    const float* a_param = (const float*)d_in[4];
    const float* v       = (const float*)d_in[5];
    const float* vu      = (const float*)d_in[6];
    // d_in[7] theta_init (unused: multiplies x==0), d_in[8] info (unused)

    float* x = (float*)d_out;                       // (B,N) + 2K zeros

    // workspace layout (88 MB total)
    char* ws = (char*)d_ws;
    float*          uz = (float*)ws;                                  // 64 MB: c fp32 / z planes
    unsigned short* bS = (unsigned short*)(ws + (size_t)Bsz * Ndim * 4); // 16 MB: b planes
    unsigned short* Ah = (unsigned short*)(ws + (size_t)80 * 1024 * 1024);
    unsigned short* Al  = Ah  + (size_t)Mdim * Ndim;                  // 2 MB each
    unsigned short* AhT = Al  + (size_t)Mdim * Ndim;
    unsigned short* AlT = AhT + (size_t)Mdim * Ndim;

    hipMemsetAsync(d_out, 0, (size_t)out_size * sizeof(float), stream);

    dim3 blk(256);
    dim3 g1(Mdim / 64, Bsz / 128);      // 8 x 64  = 512 blocks
    dim3 g2(Ndim / 128, Bsz / 128);     // 16 x 64 = 1024 blocks

    presplit_A<<<(Mdim * Ndim) / 256, blk, 0, stream>>>(A, Ah, Al, AhT, AlT);
    split_negy_kernel<<<(Bsz * Mdim / 4) / 256, blk, 0, stream>>>(y, bS);

    for (int it = 0; it < Kit; ++it) {
        if (it > 0)
            gemm1_mfma<<<g1, blk, 0, stream>>>((const unsigned short*)uz, Ah, Al, y, bS);
        gemm2_mfma<<<g2, blk, 0, stream>>>(bS, AhT, AlT, uz);
        topk_update_kernel<<<Bsz, blk, 0, stream>>>(uz, x, gamma, theta, a_param, v, vu, it);
    }
}